// Round 6
// baseline (178.554 us; speedup 1.0000x reference)
//
#include <hip/hip_runtime.h>
#include <hip/hip_bf16.h>
#include <stdint.h>

// NaN-masked euclidean distances via MX-scaled all-fp8 MFMA (unity scales).
//   prepass v6: R5's plane-specialized blocks (6 jobs x 1024 blocks, one
//               contiguous 1KB store stream per wave -- proven 36us) + NON-
//               TEMPORAL input loads. R5 lesson: the 3x re-read of X/Y (300MB)
//               streamed through L2 evicted the freshly-written ws (24MB),
//               making the latency-bound main kernel pay L3 instead of L2 on
//               every staging access (89 -> 123us on identical code). nt loads
//               keep ws L2-resident.
//   main:      EXACT R0 kernel (128x128 tile, 256 thr, 4 waves 2x2, single 48KB
//               LDS buffer, 2 barriers/K-step, 2D grid, VGPR 104, no spill)
//               + NON-TEMPORAL out stores (out is 64MB write-once; normal
//               caching evicts ws from L2 during the main loop).
//   d = xx*q + p*yy + xc*m2 ; cnt = p*q  (fp8 0/1 products -> exact)
//   out = sqrt(clip(d,0)*D/max(1,cnt)), NaN where cnt==0.
// R1-R5 lessons: AGPR=128 floor caps at 2 waves/SIMD; any VGPR>128 or LDS>80KB
// drops occupancy and loses the latency-hiding TLP; ws must stay plane-separate
// (interleaved layouts stretch staging ~2x); L2 residency of ws is worth ~35us.
// Floors: MFMA 29.3us, LDS ~41us.

typedef __bf16 bf16_t;
typedef __attribute__((ext_vector_type(8))) __bf16 bf16x8;
typedef __attribute__((ext_vector_type(4))) float floatx4;
typedef __attribute__((ext_vector_type(16))) float floatx16;
typedef __attribute__((ext_vector_type(8))) int int32x8;

#define NROWS 4096
#define MCOLS 4096
#define DDIM  1024
#define BM 128
#define BN 128
#define BK 64

// ws layout: 6 fp8 planes x 4 MB (row = 1024 B, pre-swizzled chunks)
#define WS_XX ((uint32_t)0)
#define WS_XC ((uint32_t)(4  << 20))
#define WS_P  ((uint32_t)(8  << 20))
#define WS_YY ((uint32_t)(12 << 20))
#define WS_M2 ((uint32_t)(16 << 20))
#define WS_Q  ((uint32_t)(20 << 20))
#define WS_NEEDED ((size_t)(24 << 20))

// LDS plane bases: 6 planes x 8192 B ([128 rows x 64 B])
#define L_XX 0
#define L_XC 8192
#define L_P  16384
#define L_YY 24576
#define L_M2 32768
#define L_Q  40960

// ---------------- prepass v6: plane-specialized + nontemporal input reads ----------------
// 6144 blocks x 256 thr: job = b>>10 (0:XX 1:XC 2:P | 3:YY 4:M2 5:Q), rb = b&1023,
// 4 rows/block, 16 elems/thread. Each wave: 4 nt float4 loads + one 1KB plane store.
__global__ __launch_bounds__(256)
void convert_planes_mx(const float* __restrict__ X, const float* __restrict__ Y,
                       char* __restrict__ ws) {
    int b = blockIdx.x;
    int job = b >> 10;               // uniform per block
    int rb  = b & 1023;
    bool isX = (job < 3);
    const float* src = isX ? X : Y;
    int row = rb * 4 + (threadIdx.x >> 6);
    int l = threadIdx.x & 63;
    int k0 = l << 4;

    const floatx4* p = (const floatx4*)(src + (size_t)row * DDIM + k0);
    float v[16];
    #pragma unroll
    for (int i = 0; i < 4; i++) {
        floatx4 t = __builtin_nontemporal_load(p + i);   // don't displace ws in L2
        v[4*i+0] = t[0]; v[4*i+1] = t[1]; v[4*i+2] = t[2]; v[4*i+3] = t[3];
    }
    // kind 0: squares (XX/YY); kind 1: value (XC: c, M2: -2c); kind 2: mask (P/Q)
    int kind = (job == 0 || job == 3) ? 0 : (job == 1 || job == 4) ? 1 : 2;
    float f[16];
    #pragma unroll
    for (int i = 0; i < 16; i++) {
        float x = v[i];
        bool miss = __builtin_isnan(x);
        float c = miss ? 0.f : x;
        f[i] = (kind == 0) ? c * c
             : (kind == 1) ? (isX ? c : (-2.f * c))
             :               (miss ? 0.f : 1.f);
    }
    uint32_t d[4];
    #pragma unroll
    for (int i = 0; i < 4; i++) {
        int r = __builtin_amdgcn_cvt_pk_fp8_f32(f[4*i], f[4*i+1], 0, 0);
        r     = __builtin_amdgcn_cvt_pk_fp8_f32(f[4*i+2], f[4*i+3], r, 1);
        d[i] = (uint32_t)r;
    }
    // 16B chunk swizzle inside each 64B k-group: phys = logical ^ ((row>>1)&3)
    uint32_t off8 = (uint32_t)row * 1024u + (uint32_t)(l >> 2) * 64u
                  + (uint32_t)((((l & 3) ^ ((row >> 1) & 3)) << 4));
    uint32_t base = (job == 0) ? WS_XX : (job == 1) ? WS_XC : (job == 2) ? WS_P
                  : (job == 3) ? WS_YY : (job == 4) ? WS_M2 : WS_Q;
    *(uint4*)(ws + base + off8) = make_uint4(d[0], d[1], d[2], d[3]);
}

// ---------------- main MX MFMA kernel (EXACT R0 + nt out stores) ----------------
__device__ __forceinline__ int32x8 ld32B(const char* p0, const char* p1) {
    union { int32x8 v; int4 h[2]; } u;
    u.h[0] = *(const int4*)p0;
    u.h[1] = *(const int4*)p1;
    return u.v;
}

__global__ __launch_bounds__(256, 2)
void nan_euclid_mx(const char* __restrict__ ws, float* __restrict__ out) {
    __shared__ __align__(16) char ldsb[49152];

    const int tid = threadIdx.x, lane = tid & 63, wid = tid >> 6;
    const int l31 = lane & 31, kh = lane >> 5;
    const int wrow = (wid >> 1) * 64, wcol = (wid & 1) * 64;
    const int blockRow = blockIdx.y * BM, blockCol = blockIdx.x * BN;

    // staging: 12 global_load_lds (16B) per wave per kc; identity copy (ws pre-swizzled)
    // global chunk id ch in [0,3072): plane = ch>>9 (XX,XC,P,YY,M2,Q), c2 = ch&511,
    // row = c2>>2, cc = c2&3. LDS byte = ch*16.
    uint32_t goff[12];
    #pragma unroll
    for (int t = 0; t < 12; t++) {
        int ch = (wid * 12 + t) * 64 + lane;
        int pl = ch >> 9;
        int c2 = ch & 511;
        int row = c2 >> 2, cc = c2 & 3;
        int rg = (pl < 3 ? blockRow : blockCol) + row;
        uint32_t base = (pl == 0) ? WS_XX : (pl == 1) ? WS_XC : (pl == 2) ? WS_P
                      : (pl == 3) ? WS_YY : (pl == 4) ? WS_M2 : WS_Q;
        goff[t] = base + (uint32_t)rg * 1024u + (uint32_t)(cc << 4);
    }

    // fragment-read LDS offsets (within plane); operand = 32 k-elems at k-half kh
    // logical quarters 2kh, 2kh+1; physical = logical ^ ((m>>1)&3)
    int aoff0[2], aoff1[2], boff0[2], boff1[2];
    #pragma unroll
    for (int tt = 0; tt < 2; tt++) {
        int m = wrow + tt * 32 + l31;
        int sw = (m >> 1) & 3;
        aoff0[tt] = m * 64 + (((kh * 2)     ^ sw) << 4);
        aoff1[tt] = m * 64 + (((kh * 2 + 1) ^ sw) << 4);
        int n = wcol + tt * 32 + l31;
        int swn = (n >> 1) & 3;
        boff0[tt] = n * 64 + (((kh * 2)     ^ swn) << 4);
        boff1[tt] = n * 64 + (((kh * 2 + 1) ^ swn) << 4);
    }

    floatx16 acc_d[2][2], acc_c[2][2];
    #pragma unroll
    for (int i = 0; i < 2; i++)
        #pragma unroll
        for (int j = 0; j < 2; j++)
            #pragma unroll
            for (int r = 0; r < 16; r++) { acc_d[i][j][r] = 0.f; acc_c[i][j][r] = 0.f; }

    for (int kc = 0; kc < DDIM / BK; kc++) {
        #pragma unroll
        for (int t = 0; t < 12; t++) {
            __builtin_amdgcn_global_load_lds(
                (const __attribute__((address_space(1))) void*)(ws + goff[t] + kc * 64u),
                (__attribute__((address_space(3))) void*)(ldsb + (uint32_t)((wid * 12 + t) * 1024)),
                16, 0, 0);
        }
        __syncthreads();

        int32x8 axx[2], axc[2], ap[2], byy[2], bm2[2], bq[2];
        #pragma unroll
        for (int tt = 0; tt < 2; tt++) {
            axx[tt] = ld32B(ldsb + L_XX + aoff0[tt], ldsb + L_XX + aoff1[tt]);
            axc[tt] = ld32B(ldsb + L_XC + aoff0[tt], ldsb + L_XC + aoff1[tt]);
            ap [tt] = ld32B(ldsb + L_P  + aoff0[tt], ldsb + L_P  + aoff1[tt]);
            byy[tt] = ld32B(ldsb + L_YY + boff0[tt], ldsb + L_YY + boff1[tt]);
            bm2[tt] = ld32B(ldsb + L_M2 + boff0[tt], ldsb + L_M2 + boff1[tt]);
            bq [tt] = ld32B(ldsb + L_Q  + boff0[tt], ldsb + L_Q  + boff1[tt]);
        }

        // chain-major order: dependency distance 4 insts per accumulator
        #pragma unroll
        for (int tm = 0; tm < 2; tm++)
            #pragma unroll
            for (int tn = 0; tn < 2; tn++)
                acc_d[tm][tn] = __builtin_amdgcn_mfma_scale_f32_32x32x64_f8f6f4(
                    axx[tm], bq[tn], acc_d[tm][tn], 0, 0, 0, 0x7f7f7f7f, 0, 0x7f7f7f7f);
        #pragma unroll
        for (int tm = 0; tm < 2; tm++)
            #pragma unroll
            for (int tn = 0; tn < 2; tn++)
                acc_d[tm][tn] = __builtin_amdgcn_mfma_scale_f32_32x32x64_f8f6f4(
                    ap[tm], byy[tn], acc_d[tm][tn], 0, 0, 0, 0x7f7f7f7f, 0, 0x7f7f7f7f);
        #pragma unroll
        for (int tm = 0; tm < 2; tm++)
            #pragma unroll
            for (int tn = 0; tn < 2; tn++)
                acc_d[tm][tn] = __builtin_amdgcn_mfma_scale_f32_32x32x64_f8f6f4(
                    axc[tm], bm2[tn], acc_d[tm][tn], 0, 0, 0, 0x7f7f7f7f, 0, 0x7f7f7f7f);
        #pragma unroll
        for (int tm = 0; tm < 2; tm++)
            #pragma unroll
            for (int tn = 0; tn < 2; tn++)
                acc_c[tm][tn] = __builtin_amdgcn_mfma_scale_f32_32x32x64_f8f6f4(
                    ap[tm], bq[tn], acc_c[tm][tn], 0, 0, 0, 0x7f7f7f7f, 0, 0x7f7f7f7f);

        __syncthreads();
    }

    // epilogue; 32x32 C/D layout (m74/m101): col = lane&31, row = (reg&3)+8*(reg>>2)+4*(lane>>5)
    // nt stores: out is write-once; keep it from evicting ws in L2.
    #pragma unroll
    for (int tm = 0; tm < 2; tm++) {
        #pragma unroll
        for (int tn = 0; tn < 2; tn++) {
            int col = blockCol + wcol + tn * 32 + l31;
            #pragma unroll
            for (int r = 0; r < 16; r++) {
                int rowl = (r & 3) + 8 * (r >> 2) + 4 * kh;
                int row = blockRow + wrow + tm * 32 + rowl;
                float d = fmaxf(acc_d[tm][tn][r], 0.f);
                float c = acc_c[tm][tn][r];
                float res = (c < 0.5f) ? __builtin_nanf("")
                                       : __builtin_sqrtf(d * (float)DDIM / c);
                __builtin_nontemporal_store(res, &out[(size_t)row * MCOLS + col]);
            }
        }
    }
}

// ---------------- fallback: fused single-kernel bf16 (if ws too small) ----------------
#define LDK 40
__global__ __launch_bounds__(256, 2)
void nan_euclid_fused(const float* __restrict__ X, const float* __restrict__ Y,
                      float* __restrict__ out) {
    typedef __attribute__((ext_vector_type(4))) __bf16 bf16x4;
    __shared__ bf16_t s_xx[BM * LDK];
    __shared__ bf16_t s_p [BM * LDK];
    __shared__ bf16_t s_xc[BM * LDK];
    __shared__ bf16_t s_q [BN * LDK];
    __shared__ bf16_t s_yy[BN * LDK];
    __shared__ bf16_t s_m2[BN * LDK];

    const int tid  = threadIdx.x;
    const int lane = tid & 63;
    const int wid  = tid >> 6;
    const int quad = lane >> 4;
    const int r16  = lane & 15;
    const int wrow = (wid >> 1) * 64;
    const int wcol = (wid & 1) * 64;
    const int blockRow = blockIdx.y * BM;
    const int blockCol = blockIdx.x * BN;

    floatx4 acc_d[4][4];
    floatx4 acc_c[4][4];
    #pragma unroll
    for (int i = 0; i < 4; i++)
        #pragma unroll
        for (int j = 0; j < 4; j++)
            #pragma unroll
            for (int r = 0; r < 4; r++) { acc_d[i][j][r] = 0.f; acc_c[i][j][r] = 0.f; }

    for (int kc = 0; kc < DDIM / 32; kc++) {
        const int kbase = kc * 32;
        #pragma unroll
        for (int i = 0; i < 4; i++) {
            int idx = tid + 256 * i;
            int row = idx >> 3;
            int c4  = idx & 7;
            const float4 v = *(const float4*)(X + (size_t)(blockRow + row) * DDIM + kbase + c4 * 4);
            bf16x4 vxc, vxx, vp;
            const float xs[4] = {v.x, v.y, v.z, v.w};
            #pragma unroll
            for (int e = 0; e < 4; e++) {
                float x = xs[e];
                bool miss = __builtin_isnan(x);
                float xc = miss ? 0.f : x;
                vxc[e] = (bf16_t)xc;
                vxx[e] = (bf16_t)(xc * xc);
                vp[e]  = miss ? (bf16_t)0.f : (bf16_t)1.f;
            }
            int off = row * LDK + c4 * 4;
            *(bf16x4*)&s_xc[off] = vxc;
            *(bf16x4*)&s_xx[off] = vxx;
            *(bf16x4*)&s_p [off] = vp;
        }
        #pragma unroll
        for (int i = 0; i < 4; i++) {
            int idx = tid + 256 * i;
            int row = idx >> 3;
            int c4  = idx & 7;
            const float4 v = *(const float4*)(Y + (size_t)(blockCol + row) * DDIM + kbase + c4 * 4);
            bf16x4 vq, vyy, vm2;
            const float ys[4] = {v.x, v.y, v.z, v.w};
            #pragma unroll
            for (int e = 0; e < 4; e++) {
                float y = ys[e];
                bool miss = __builtin_isnan(y);
                float yc = miss ? 0.f : y;
                vq[e]  = miss ? (bf16_t)0.f : (bf16_t)1.f;
                vyy[e] = (bf16_t)(yc * yc);
                vm2[e] = (bf16_t)(-2.f * yc);
            }
            int off = row * LDK + c4 * 4;
            *(bf16x4*)&s_q [off] = vq;
            *(bf16x4*)&s_yy[off] = vyy;
            *(bf16x4*)&s_m2[off] = vm2;
        }
        __syncthreads();
        bf16x8 bq[4], byy[4], bm2[4];
        #pragma unroll
        for (int tn = 0; tn < 4; tn++) {
            int off = (wcol + tn * 16 + r16) * LDK + quad * 8;
            bq[tn]  = *(const bf16x8*)&s_q [off];
            byy[tn] = *(const bf16x8*)&s_yy[off];
            bm2[tn] = *(const bf16x8*)&s_m2[off];
        }
        #pragma unroll
        for (int tm = 0; tm < 4; tm++) {
            int off = (wrow + tm * 16 + r16) * LDK + quad * 8;
            bf16x8 axx = *(const bf16x8*)&s_xx[off];
            bf16x8 ap  = *(const bf16x8*)&s_p [off];
            bf16x8 axc = *(const bf16x8*)&s_xc[off];
            #pragma unroll
            for (int tn = 0; tn < 4; tn++) {
                acc_d[tm][tn] = __builtin_amdgcn_mfma_f32_16x16x32_bf16(axx, bq[tn],  acc_d[tm][tn], 0, 0, 0);
                acc_d[tm][tn] = __builtin_amdgcn_mfma_f32_16x16x32_bf16(ap,  byy[tn], acc_d[tm][tn], 0, 0, 0);
                acc_d[tm][tn] = __builtin_amdgcn_mfma_f32_16x16x32_bf16(axc, bm2[tn], acc_d[tm][tn], 0, 0, 0);
                acc_c[tm][tn] = __builtin_amdgcn_mfma_f32_16x16x32_bf16(ap,  bq[tn],  acc_c[tm][tn], 0, 0, 0);
            }
        }
        __syncthreads();
    }
    #pragma unroll
    for (int tm = 0; tm < 4; tm++) {
        #pragma unroll
        for (int tn = 0; tn < 4; tn++) {
            int col = blockCol + wcol + tn * 16 + r16;
            #pragma unroll
            for (int r = 0; r < 4; r++) {
                int row = blockRow + wrow + tm * 16 + quad * 4 + r;
                float d = acc_d[tm][tn][r];
                float c = acc_c[tm][tn][r];
                d = fmaxf(d, 0.f);
                float res = (c < 0.5f) ? __builtin_nanf("")
                                       : __builtin_sqrtf(d * (float)DDIM / c);
                out[(size_t)row * MCOLS + col] = res;
            }
        }
    }
}

extern "C" void kernel_launch(void* const* d_in, const int* in_sizes, int n_in,
                              void* d_out, int out_size, void* d_ws, size_t ws_size,
                              hipStream_t stream) {
    const float* X = (const float*)d_in[0];
    const float* Y = (const float*)d_in[1];
    float* out = (float*)d_out;

    if (ws_size >= WS_NEEDED) {
        char* ws = (char*)d_ws;
        convert_planes_mx<<<dim3(6144), dim3(256), 0, stream>>>(X, Y, ws);
        dim3 grid(MCOLS / BN, NROWS / BM);
        nan_euclid_mx<<<grid, dim3(256), 0, stream>>>(ws, out);
    } else {
        dim3 grid(MCOLS / BN, NROWS / BM);
        nan_euclid_fused<<<grid, dim3(256), 0, stream>>>(X, Y, out);
    }
}

// Round 7
// 168.666 us; speedup vs baseline: 1.0586x; 1.0586x over previous
//
#include <hip/hip_runtime.h>
#include <hip/hip_bf16.h>
#include <stdint.h>

// NaN-masked euclidean distances via MX-scaled all-fp8 MFMA (unity scales).
//   prepass v7: plane-specialized blocks (6 jobs x 1024 blocks; one plane per
//               block -> single store stream) + NON-TEMPORAL input loads with
//               WAVE-CONTIGUOUS pattern: thread tid at step j reads row rb*4+j,
//               elems [4*tid,4*tid+4) -> each nt instruction covers a contiguous
//               1KB, every 64B line fully consumed in ONE instruction.
//               R6 lesson: nt + stride-64 lane pattern re-fetched each line 4x
//               from HBM (prepass 44->88us). nt is required so the 3x X/Y
//               re-read doesn't evict ws from L2 (R5 lesson: that stretched the
//               latency-bound main kernel 89->123us on identical code).
//   main:      EXACT R0 kernel (128x128 tile, 256 thr, 4 waves 2x2, single 48KB
//               LDS buffer, 2 barriers/K-step, 2D grid, VGPR 104, no spill)
//               + nt out stores (write-once stream; don't evict ws from L2).
//   d = xx*q + p*yy + xc*m2 ; cnt = p*q  (fp8 0/1 products -> exact)
//   out = sqrt(clip(d,0)*D/max(1,cnt)), NaN where cnt==0.
// R1-R6 lessons: AGPR=128 floor caps at 2 waves/SIMD; VGPR>128 or LDS>80KB
// kills the latency-hiding TLP; ws must stay plane-separate AND L2-resident
// (worth ~33us); nt loads need per-instruction-contiguous lane patterns.
// Floors: MFMA 29.3us, LDS ~41us, prepass HBM ~20us.

typedef __bf16 bf16_t;
typedef __attribute__((ext_vector_type(8))) __bf16 bf16x8;
typedef __attribute__((ext_vector_type(4))) float floatx4;
typedef __attribute__((ext_vector_type(16))) float floatx16;
typedef __attribute__((ext_vector_type(8))) int int32x8;

#define NROWS 4096
#define MCOLS 4096
#define DDIM  1024
#define BM 128
#define BN 128
#define BK 64

// ws layout: 6 fp8 planes x 4 MB (row = 1024 B, pre-swizzled chunks)
#define WS_XX ((uint32_t)0)
#define WS_XC ((uint32_t)(4  << 20))
#define WS_P  ((uint32_t)(8  << 20))
#define WS_YY ((uint32_t)(12 << 20))
#define WS_M2 ((uint32_t)(16 << 20))
#define WS_Q  ((uint32_t)(20 << 20))
#define WS_NEEDED ((size_t)(24 << 20))

// LDS plane bases: 6 planes x 8192 B ([128 rows x 64 B])
#define L_XX 0
#define L_XC 8192
#define L_P  16384
#define L_YY 24576
#define L_M2 32768
#define L_Q  40960

// ---------------- prepass v7: plane-specialized + wave-contiguous nt reads ----------------
// 6144 blocks x 256 thr: job = b>>10 (0:XX 1:XC 2:P | 3:YY 4:M2 5:Q), rb = b&1023.
// Block covers 4 rows; step j handles row rb*4+j; thread tid: elems [4*tid, 4*tid+4).
__global__ __launch_bounds__(256)
void convert_planes_mx(const float* __restrict__ X, const float* __restrict__ Y,
                       char* __restrict__ ws) {
    int b = blockIdx.x;
    int job = b >> 10;               // uniform per block
    int rb  = b & 1023;
    bool isX = (job < 3);
    const float* src = isX ? X : Y;
    int tid = threadIdx.x;

    // kind 0: squares (XX/YY); kind 1: value (XC: c, M2: -2c); kind 2: mask (P/Q)
    int kind = (job == 0 || job == 3) ? 0 : (job == 1 || job == 4) ? 1 : 2;
    uint32_t base = (job == 0) ? WS_XX : (job == 1) ? WS_XC : (job == 2) ? WS_P
                  : (job == 3) ? WS_YY : (job == 4) ? WS_M2 : WS_Q;

    // store position pieces independent of row: 64B group g=tid>>4, chunk (tid>>2)&3,
    // byte-in-chunk (tid&3)*4. Swizzle: phys chunk = logical ^ ((row>>1)&3).
    uint32_t gpart = (uint32_t)((tid >> 4) << 6) + (uint32_t)((tid & 3) << 2);
    uint32_t cl = ((uint32_t)tid >> 2) & 3u;

    #pragma unroll
    for (int j = 0; j < 4; j++) {
        int row = rb * 4 + j;
        const floatx4* p = (const floatx4*)(src + (size_t)row * DDIM) + tid;
        floatx4 t = __builtin_nontemporal_load(p);   // wave reads contiguous 1KB
        float f[4];
        #pragma unroll
        for (int i = 0; i < 4; i++) {
            float x = t[i];
            bool miss = __builtin_isnan(x);
            float c = miss ? 0.f : x;
            f[i] = (kind == 0) ? c * c
                 : (kind == 1) ? (isX ? c : (-2.f * c))
                 :               (miss ? 0.f : 1.f);
        }
        int r = __builtin_amdgcn_cvt_pk_fp8_f32(f[0], f[1], 0, 0);
        r     = __builtin_amdgcn_cvt_pk_fp8_f32(f[2], f[3], r, 1);
        uint32_t sw = ((uint32_t)row >> 1) & 3u;
        uint32_t off = (uint32_t)row * 1024u + gpart + ((cl ^ sw) << 4);
        *(uint32_t*)(ws + base + off) = (uint32_t)r;   // cached: allocates ws in L2
    }
}

// ---------------- main MX MFMA kernel (EXACT R0 + nt out stores) ----------------
__device__ __forceinline__ int32x8 ld32B(const char* p0, const char* p1) {
    union { int32x8 v; int4 h[2]; } u;
    u.h[0] = *(const int4*)p0;
    u.h[1] = *(const int4*)p1;
    return u.v;
}

__global__ __launch_bounds__(256, 2)
void nan_euclid_mx(const char* __restrict__ ws, float* __restrict__ out) {
    __shared__ __align__(16) char ldsb[49152];

    const int tid = threadIdx.x, lane = tid & 63, wid = tid >> 6;
    const int l31 = lane & 31, kh = lane >> 5;
    const int wrow = (wid >> 1) * 64, wcol = (wid & 1) * 64;
    const int blockRow = blockIdx.y * BM, blockCol = blockIdx.x * BN;

    // staging: 12 global_load_lds (16B) per wave per kc; identity copy (ws pre-swizzled)
    // global chunk id ch in [0,3072): plane = ch>>9 (XX,XC,P,YY,M2,Q), c2 = ch&511,
    // row = c2>>2, cc = c2&3. LDS byte = ch*16.
    uint32_t goff[12];
    #pragma unroll
    for (int t = 0; t < 12; t++) {
        int ch = (wid * 12 + t) * 64 + lane;
        int pl = ch >> 9;
        int c2 = ch & 511;
        int row = c2 >> 2, cc = c2 & 3;
        int rg = (pl < 3 ? blockRow : blockCol) + row;
        uint32_t base = (pl == 0) ? WS_XX : (pl == 1) ? WS_XC : (pl == 2) ? WS_P
                      : (pl == 3) ? WS_YY : (pl == 4) ? WS_M2 : WS_Q;
        goff[t] = base + (uint32_t)rg * 1024u + (uint32_t)(cc << 4);
    }

    // fragment-read LDS offsets (within plane); operand = 32 k-elems at k-half kh
    // logical quarters 2kh, 2kh+1; physical = logical ^ ((m>>1)&3)
    int aoff0[2], aoff1[2], boff0[2], boff1[2];
    #pragma unroll
    for (int tt = 0; tt < 2; tt++) {
        int m = wrow + tt * 32 + l31;
        int sw = (m >> 1) & 3;
        aoff0[tt] = m * 64 + (((kh * 2)     ^ sw) << 4);
        aoff1[tt] = m * 64 + (((kh * 2 + 1) ^ sw) << 4);
        int n = wcol + tt * 32 + l31;
        int swn = (n >> 1) & 3;
        boff0[tt] = n * 64 + (((kh * 2)     ^ swn) << 4);
        boff1[tt] = n * 64 + (((kh * 2 + 1) ^ swn) << 4);
    }

    floatx16 acc_d[2][2], acc_c[2][2];
    #pragma unroll
    for (int i = 0; i < 2; i++)
        #pragma unroll
        for (int j = 0; j < 2; j++)
            #pragma unroll
            for (int r = 0; r < 16; r++) { acc_d[i][j][r] = 0.f; acc_c[i][j][r] = 0.f; }

    for (int kc = 0; kc < DDIM / BK; kc++) {
        #pragma unroll
        for (int t = 0; t < 12; t++) {
            __builtin_amdgcn_global_load_lds(
                (const __attribute__((address_space(1))) void*)(ws + goff[t] + kc * 64u),
                (__attribute__((address_space(3))) void*)(ldsb + (uint32_t)((wid * 12 + t) * 1024)),
                16, 0, 0);
        }
        __syncthreads();

        int32x8 axx[2], axc[2], ap[2], byy[2], bm2[2], bq[2];
        #pragma unroll
        for (int tt = 0; tt < 2; tt++) {
            axx[tt] = ld32B(ldsb + L_XX + aoff0[tt], ldsb + L_XX + aoff1[tt]);
            axc[tt] = ld32B(ldsb + L_XC + aoff0[tt], ldsb + L_XC + aoff1[tt]);
            ap [tt] = ld32B(ldsb + L_P  + aoff0[tt], ldsb + L_P  + aoff1[tt]);
            byy[tt] = ld32B(ldsb + L_YY + boff0[tt], ldsb + L_YY + boff1[tt]);
            bm2[tt] = ld32B(ldsb + L_M2 + boff0[tt], ldsb + L_M2 + boff1[tt]);
            bq [tt] = ld32B(ldsb + L_Q  + boff0[tt], ldsb + L_Q  + boff1[tt]);
        }

        // chain-major order: dependency distance 4 insts per accumulator
        #pragma unroll
        for (int tm = 0; tm < 2; tm++)
            #pragma unroll
            for (int tn = 0; tn < 2; tn++)
                acc_d[tm][tn] = __builtin_amdgcn_mfma_scale_f32_32x32x64_f8f6f4(
                    axx[tm], bq[tn], acc_d[tm][tn], 0, 0, 0, 0x7f7f7f7f, 0, 0x7f7f7f7f);
        #pragma unroll
        for (int tm = 0; tm < 2; tm++)
            #pragma unroll
            for (int tn = 0; tn < 2; tn++)
                acc_d[tm][tn] = __builtin_amdgcn_mfma_scale_f32_32x32x64_f8f6f4(
                    ap[tm], byy[tn], acc_d[tm][tn], 0, 0, 0, 0x7f7f7f7f, 0, 0x7f7f7f7f);
        #pragma unroll
        for (int tm = 0; tm < 2; tm++)
            #pragma unroll
            for (int tn = 0; tn < 2; tn++)
                acc_d[tm][tn] = __builtin_amdgcn_mfma_scale_f32_32x32x64_f8f6f4(
                    axc[tm], bm2[tn], acc_d[tm][tn], 0, 0, 0, 0x7f7f7f7f, 0, 0x7f7f7f7f);
        #pragma unroll
        for (int tm = 0; tm < 2; tm++)
            #pragma unroll
            for (int tn = 0; tn < 2; tn++)
                acc_c[tm][tn] = __builtin_amdgcn_mfma_scale_f32_32x32x64_f8f6f4(
                    ap[tm], bq[tn], acc_c[tm][tn], 0, 0, 0, 0x7f7f7f7f, 0, 0x7f7f7f7f);

        __syncthreads();
    }

    // epilogue; 32x32 C/D layout (m74/m101): col = lane&31, row = (reg&3)+8*(reg>>2)+4*(lane>>5)
    // nt stores: out is write-once; keep it from evicting ws in L2.
    #pragma unroll
    for (int tm = 0; tm < 2; tm++) {
        #pragma unroll
        for (int tn = 0; tn < 2; tn++) {
            int col = blockCol + wcol + tn * 32 + l31;
            #pragma unroll
            for (int r = 0; r < 16; r++) {
                int rowl = (r & 3) + 8 * (r >> 2) + 4 * kh;
                int row = blockRow + wrow + tm * 32 + rowl;
                float d = fmaxf(acc_d[tm][tn][r], 0.f);
                float c = acc_c[tm][tn][r];
                float res = (c < 0.5f) ? __builtin_nanf("")
                                       : __builtin_sqrtf(d * (float)DDIM / c);
                __builtin_nontemporal_store(res, &out[(size_t)row * MCOLS + col]);
            }
        }
    }
}

// ---------------- fallback: fused single-kernel bf16 (if ws too small) ----------------
#define LDK 40
__global__ __launch_bounds__(256, 2)
void nan_euclid_fused(const float* __restrict__ X, const float* __restrict__ Y,
                      float* __restrict__ out) {
    typedef __attribute__((ext_vector_type(4))) __bf16 bf16x4;
    __shared__ bf16_t s_xx[BM * LDK];
    __shared__ bf16_t s_p [BM * LDK];
    __shared__ bf16_t s_xc[BM * LDK];
    __shared__ bf16_t s_q [BN * LDK];
    __shared__ bf16_t s_yy[BN * LDK];
    __shared__ bf16_t s_m2[BN * LDK];

    const int tid  = threadIdx.x;
    const int lane = tid & 63;
    const int wid  = tid >> 6;
    const int quad = lane >> 4;
    const int r16  = lane & 15;
    const int wrow = (wid >> 1) * 64;
    const int wcol = (wid & 1) * 64;
    const int blockRow = blockIdx.y * BM;
    const int blockCol = blockIdx.x * BN;

    floatx4 acc_d[4][4];
    floatx4 acc_c[4][4];
    #pragma unroll
    for (int i = 0; i < 4; i++)
        #pragma unroll
        for (int j = 0; j < 4; j++)
            #pragma unroll
            for (int r = 0; r < 4; r++) { acc_d[i][j][r] = 0.f; acc_c[i][j][r] = 0.f; }

    for (int kc = 0; kc < DDIM / 32; kc++) {
        const int kbase = kc * 32;
        #pragma unroll
        for (int i = 0; i < 4; i++) {
            int idx = tid + 256 * i;
            int row = idx >> 3;
            int c4  = idx & 7;
            const float4 v = *(const float4*)(X + (size_t)(blockRow + row) * DDIM + kbase + c4 * 4);
            bf16x4 vxc, vxx, vp;
            const float xs[4] = {v.x, v.y, v.z, v.w};
            #pragma unroll
            for (int e = 0; e < 4; e++) {
                float x = xs[e];
                bool miss = __builtin_isnan(x);
                float xc = miss ? 0.f : x;
                vxc[e] = (bf16_t)xc;
                vxx[e] = (bf16_t)(xc * xc);
                vp[e]  = miss ? (bf16_t)0.f : (bf16_t)1.f;
            }
            int off = row * LDK + c4 * 4;
            *(bf16x4*)&s_xc[off] = vxc;
            *(bf16x4*)&s_xx[off] = vxx;
            *(bf16x4*)&s_p [off] = vp;
        }
        #pragma unroll
        for (int i = 0; i < 4; i++) {
            int idx = tid + 256 * i;
            int row = idx >> 3;
            int c4  = idx & 7;
            const float4 v = *(const float4*)(Y + (size_t)(blockCol + row) * DDIM + kbase + c4 * 4);
            bf16x4 vq, vyy, vm2;
            const float ys[4] = {v.x, v.y, v.z, v.w};
            #pragma unroll
            for (int e = 0; e < 4; e++) {
                float y = ys[e];
                bool miss = __builtin_isnan(y);
                float yc = miss ? 0.f : y;
                vq[e]  = miss ? (bf16_t)0.f : (bf16_t)1.f;
                vyy[e] = (bf16_t)(yc * yc);
                vm2[e] = (bf16_t)(-2.f * yc);
            }
            int off = row * LDK + c4 * 4;
            *(bf16x4*)&s_q [off] = vq;
            *(bf16x4*)&s_yy[off] = vyy;
            *(bf16x4*)&s_m2[off] = vm2;
        }
        __syncthreads();
        bf16x8 bq[4], byy[4], bm2[4];
        #pragma unroll
        for (int tn = 0; tn < 4; tn++) {
            int off = (wcol + tn * 16 + r16) * LDK + quad * 8;
            bq[tn]  = *(const bf16x8*)&s_q [off];
            byy[tn] = *(const bf16x8*)&s_yy[off];
            bm2[tn] = *(const bf16x8*)&s_m2[off];
        }
        #pragma unroll
        for (int tm = 0; tm < 4; tm++) {
            int off = (wrow + tm * 16 + r16) * LDK + quad * 8;
            bf16x8 axx = *(const bf16x8*)&s_xx[off];
            bf16x8 ap  = *(const bf16x8*)&s_p [off];
            bf16x8 axc = *(const bf16x8*)&s_xc[off];
            #pragma unroll
            for (int tn = 0; tn < 4; tn++) {
                acc_d[tm][tn] = __builtin_amdgcn_mfma_f32_16x16x32_bf16(axx, bq[tn],  acc_d[tm][tn], 0, 0, 0);
                acc_d[tm][tn] = __builtin_amdgcn_mfma_f32_16x16x32_bf16(ap,  byy[tn], acc_d[tm][tn], 0, 0, 0);
                acc_d[tm][tn] = __builtin_amdgcn_mfma_f32_16x16x32_bf16(axc, bm2[tn], acc_d[tm][tn], 0, 0, 0);
                acc_c[tm][tn] = __builtin_amdgcn_mfma_f32_16x16x32_bf16(ap,  bq[tn],  acc_c[tm][tn], 0, 0, 0);
            }
        }
        __syncthreads();
    }
    #pragma unroll
    for (int tm = 0; tm < 4; tm++) {
        #pragma unroll
        for (int tn = 0; tn < 4; tn++) {
            int col = blockCol + wcol + tn * 16 + r16;
            #pragma unroll
            for (int r = 0; r < 4; r++) {
                int row = blockRow + wrow + tm * 16 + quad * 4 + r;
                float d = acc_d[tm][tn][r];
                float c = acc_c[tm][tn][r];
                d = fmaxf(d, 0.f);
                float res = (c < 0.5f) ? __builtin_nanf("")
                                       : __builtin_sqrtf(d * (float)DDIM / c);
                out[(size_t)row * MCOLS + col] = res;
            }
        }
    }
}

extern "C" void kernel_launch(void* const* d_in, const int* in_sizes, int n_in,
                              void* d_out, int out_size, void* d_ws, size_t ws_size,
                              hipStream_t stream) {
    const float* X = (const float*)d_in[0];
    const float* Y = (const float*)d_in[1];
    float* out = (float*)d_out;

    if (ws_size >= WS_NEEDED) {
        char* ws = (char*)d_ws;
        convert_planes_mx<<<dim3(6144), dim3(256), 0, stream>>>(X, Y, ws);
        dim3 grid(MCOLS / BN, NROWS / BM);
        nan_euclid_mx<<<grid, dim3(256), 0, stream>>>(ws, out);
    } else {
        dim3 grid(MCOLS / BN, NROWS / BM);
        nan_euclid_fused<<<grid, dim3(256), 0, stream>>>(X, Y, out);
    }
}

// Round 8
// 164.392 us; speedup vs baseline: 1.0861x; 1.0260x over previous
//
#include <hip/hip_runtime.h>
#include <hip/hip_bf16.h>
#include <stdint.h>

// NaN-masked euclidean distances via MX-scaled all-fp8 MFMA (unity scales).
//   prepass v8: READ-ONCE + LDS BOUNCE. 2048 blocks x 4 rows:
//     phase 1: nt wave-contiguous float4 loads (each input read EXACTLY once;
//              nt keeps ws L2-resident per R5/R6 lessons), convert to all 3
//              fp8 planes in-register, stage into a 12KB LDS image laid out
//              as ws ([plane][row][1KB], pre-swizzled chunks).
//     phase 2: one barrier; store iter i = plane i, each wave emits one
//              contiguous 1KB cached store per iter (single-stream per wave,
//              R4/R5 lesson; cached -> ws allocates into L2).
//   R7 lesson: 3x nt re-reads = full-latency HBM round trips, no cache reuse
//   (prepass stuck ~78us despite only 100MB). Read-once removes the re-read.
//   main: EXACT R0 kernel (128x128 tile, 256 thr, 4 waves 2x2, single 48KB
//         LDS buffer, 2 barriers/K-step, 2D grid, VGPR 104, no spill)
//         + nt out stores (write-once stream; don't evict ws from L2).
//   d = xx*q + p*yy + xc*m2 ; cnt = p*q  (fp8 0/1 products -> exact)
//   out = sqrt(clip(d,0)*D/max(1,cnt)), NaN where cnt==0.
// R1-R7 lessons: AGPR=128 floor caps at 2 waves/SIMD; VGPR>128 or LDS>80KB in
// main kills the latency-hiding TLP; ws must stay plane-separate AND
// L2-resident (worth ~33us on main); nt loads need per-instruction-contiguous
// lane patterns AND read-once volume. Floors: MFMA 29.3us, LDS ~41us.

typedef __bf16 bf16_t;
typedef __attribute__((ext_vector_type(8))) __bf16 bf16x8;
typedef __attribute__((ext_vector_type(4))) float floatx4;
typedef __attribute__((ext_vector_type(16))) float floatx16;
typedef __attribute__((ext_vector_type(8))) int int32x8;

#define NROWS 4096
#define MCOLS 4096
#define DDIM  1024
#define BM 128
#define BN 128
#define BK 64

// ws layout: 6 fp8 planes x 4 MB (row = 1024 B, pre-swizzled chunks)
#define WS_XX ((uint32_t)0)
#define WS_XC ((uint32_t)(4  << 20))
#define WS_P  ((uint32_t)(8  << 20))
#define WS_YY ((uint32_t)(12 << 20))
#define WS_M2 ((uint32_t)(16 << 20))
#define WS_Q  ((uint32_t)(20 << 20))
#define WS_NEEDED ((size_t)(24 << 20))

// LDS plane bases (main): 6 planes x 8192 B ([128 rows x 64 B])
#define L_XX 0
#define L_XC 8192
#define L_P  16384
#define L_YY 24576
#define L_M2 32768
#define L_Q  40960

// ---------------- prepass v8: read-once, LDS bounce, plane-stream stores ----------------
// 2048 blocks x 256 thr: block b -> isX = b<1024, rows [rb*4, rb*4+4).
// Phase 1 (j=0..3): thread tid nt-loads row's float4 at elems [4*tid,4*tid+4)
//   (wave covers contiguous 1KB), converts to 3 fp8 dwords, writes LDS image
//   [plane][j][1KB] at the pre-swizzled chunk position.
// Phase 2 (i=0..2): plane i, thread tid stores 16B: dst = base[i]+rowbase*1024+tid*16.
__global__ __launch_bounds__(256)
void convert_planes_mx(const float* __restrict__ X, const float* __restrict__ Y,
                       char* __restrict__ ws) {
    __shared__ __align__(16) char lds[3 * 4096];   // [plane][row 0..3][1KB]
    int b = blockIdx.x;
    bool isX = (b < 1024);
    const float* src = isX ? X : Y;
    int rb = isX ? b : b - 1024;
    int rowbase = rb * 4;
    int tid = threadIdx.x;

    // store position pieces independent of row: 64B group g=tid>>4, chunk (tid>>2)&3,
    // byte-in-chunk (tid&3)*4. Swizzle: phys chunk = logical ^ ((row>>1)&3).
    uint32_t gpart = (uint32_t)((tid >> 4) << 6) + (uint32_t)((tid & 3) << 2);
    uint32_t cl = ((uint32_t)tid >> 2) & 3u;

    #pragma unroll
    for (int j = 0; j < 4; j++) {
        int row = rowbase + j;
        const floatx4* p = (const floatx4*)(src + (size_t)row * DDIM) + tid;
        floatx4 t = __builtin_nontemporal_load(p);   // read-once; don't displace ws
        float fsq[4], fval[4], fm[4];
        #pragma unroll
        for (int i = 0; i < 4; i++) {
            float x = t[i];
            bool miss = __builtin_isnan(x);
            float c = miss ? 0.f : x;
            fsq[i]  = c * c;
            fval[i] = isX ? c : (-2.f * c);
            fm[i]   = miss ? 0.f : 1.f;
        }
        int dsq = __builtin_amdgcn_cvt_pk_fp8_f32(fsq[0], fsq[1], 0, 0);
        dsq     = __builtin_amdgcn_cvt_pk_fp8_f32(fsq[2], fsq[3], dsq, 1);
        int dvl = __builtin_amdgcn_cvt_pk_fp8_f32(fval[0], fval[1], 0, 0);
        dvl     = __builtin_amdgcn_cvt_pk_fp8_f32(fval[2], fval[3], dvl, 1);
        int dm  = __builtin_amdgcn_cvt_pk_fp8_f32(fm[0], fm[1], 0, 0);
        dm      = __builtin_amdgcn_cvt_pk_fp8_f32(fm[2], fm[3], dm, 1);
        uint32_t sw = ((uint32_t)row >> 1) & 3u;
        uint32_t loff = (uint32_t)(j << 10) + gpart + ((cl ^ sw) << 4);
        *(uint32_t*)(lds +    0 + loff) = (uint32_t)dsq;   // plane 0: XX/YY
        *(uint32_t*)(lds + 4096 + loff) = (uint32_t)dvl;   // plane 1: XC/M2
        *(uint32_t*)(lds + 8192 + loff) = (uint32_t)dm;    // plane 2: P/Q
    }
    __syncthreads();

    // phase 2: 3 x 4KB plane images -> ws (cached stores allocate ws into L2).
    // Each wave: 64 x 16B = contiguous 1KB per iter. 4KB plane region is
    // contiguous in ws (4 consecutive rows x 1KB).
    uint32_t base0 = isX ? WS_XX : WS_YY;
    uint32_t base1 = isX ? WS_XC : WS_M2;
    uint32_t base2 = isX ? WS_P  : WS_Q;
    uint32_t rbyte = (uint32_t)rowbase * 1024u + (uint32_t)(tid << 4);
    *(uint4*)(ws + base0 + rbyte) = *(const uint4*)(lds +    0 + (tid << 4));
    *(uint4*)(ws + base1 + rbyte) = *(const uint4*)(lds + 4096 + (tid << 4));
    *(uint4*)(ws + base2 + rbyte) = *(const uint4*)(lds + 8192 + (tid << 4));
}

// ---------------- main MX MFMA kernel (EXACT R0 + nt out stores) ----------------
__device__ __forceinline__ int32x8 ld32B(const char* p0, const char* p1) {
    union { int32x8 v; int4 h[2]; } u;
    u.h[0] = *(const int4*)p0;
    u.h[1] = *(const int4*)p1;
    return u.v;
}

__global__ __launch_bounds__(256, 2)
void nan_euclid_mx(const char* __restrict__ ws, float* __restrict__ out) {
    __shared__ __align__(16) char ldsb[49152];

    const int tid = threadIdx.x, lane = tid & 63, wid = tid >> 6;
    const int l31 = lane & 31, kh = lane >> 5;
    const int wrow = (wid >> 1) * 64, wcol = (wid & 1) * 64;
    const int blockRow = blockIdx.y * BM, blockCol = blockIdx.x * BN;

    // staging: 12 global_load_lds (16B) per wave per kc; identity copy (ws pre-swizzled)
    // global chunk id ch in [0,3072): plane = ch>>9 (XX,XC,P,YY,M2,Q), c2 = ch&511,
    // row = c2>>2, cc = c2&3. LDS byte = ch*16.
    uint32_t goff[12];
    #pragma unroll
    for (int t = 0; t < 12; t++) {
        int ch = (wid * 12 + t) * 64 + lane;
        int pl = ch >> 9;
        int c2 = ch & 511;
        int row = c2 >> 2, cc = c2 & 3;
        int rg = (pl < 3 ? blockRow : blockCol) + row;
        uint32_t base = (pl == 0) ? WS_XX : (pl == 1) ? WS_XC : (pl == 2) ? WS_P
                      : (pl == 3) ? WS_YY : (pl == 4) ? WS_M2 : WS_Q;
        goff[t] = base + (uint32_t)rg * 1024u + (uint32_t)(cc << 4);
    }

    // fragment-read LDS offsets (within plane); operand = 32 k-elems at k-half kh
    // logical quarters 2kh, 2kh+1; physical = logical ^ ((m>>1)&3)
    int aoff0[2], aoff1[2], boff0[2], boff1[2];
    #pragma unroll
    for (int tt = 0; tt < 2; tt++) {
        int m = wrow + tt * 32 + l31;
        int sw = (m >> 1) & 3;
        aoff0[tt] = m * 64 + (((kh * 2)     ^ sw) << 4);
        aoff1[tt] = m * 64 + (((kh * 2 + 1) ^ sw) << 4);
        int n = wcol + tt * 32 + l31;
        int swn = (n >> 1) & 3;
        boff0[tt] = n * 64 + (((kh * 2)     ^ swn) << 4);
        boff1[tt] = n * 64 + (((kh * 2 + 1) ^ swn) << 4);
    }

    floatx16 acc_d[2][2], acc_c[2][2];
    #pragma unroll
    for (int i = 0; i < 2; i++)
        #pragma unroll
        for (int j = 0; j < 2; j++)
            #pragma unroll
            for (int r = 0; r < 16; r++) { acc_d[i][j][r] = 0.f; acc_c[i][j][r] = 0.f; }

    for (int kc = 0; kc < DDIM / BK; kc++) {
        #pragma unroll
        for (int t = 0; t < 12; t++) {
            __builtin_amdgcn_global_load_lds(
                (const __attribute__((address_space(1))) void*)(ws + goff[t] + kc * 64u),
                (__attribute__((address_space(3))) void*)(ldsb + (uint32_t)((wid * 12 + t) * 1024)),
                16, 0, 0);
        }
        __syncthreads();

        int32x8 axx[2], axc[2], ap[2], byy[2], bm2[2], bq[2];
        #pragma unroll
        for (int tt = 0; tt < 2; tt++) {
            axx[tt] = ld32B(ldsb + L_XX + aoff0[tt], ldsb + L_XX + aoff1[tt]);
            axc[tt] = ld32B(ldsb + L_XC + aoff0[tt], ldsb + L_XC + aoff1[tt]);
            ap [tt] = ld32B(ldsb + L_P  + aoff0[tt], ldsb + L_P  + aoff1[tt]);
            byy[tt] = ld32B(ldsb + L_YY + boff0[tt], ldsb + L_YY + boff1[tt]);
            bm2[tt] = ld32B(ldsb + L_M2 + boff0[tt], ldsb + L_M2 + boff1[tt]);
            bq [tt] = ld32B(ldsb + L_Q  + boff0[tt], ldsb + L_Q  + boff1[tt]);
        }

        // chain-major order: dependency distance 4 insts per accumulator
        #pragma unroll
        for (int tm = 0; tm < 2; tm++)
            #pragma unroll
            for (int tn = 0; tn < 2; tn++)
                acc_d[tm][tn] = __builtin_amdgcn_mfma_scale_f32_32x32x64_f8f6f4(
                    axx[tm], bq[tn], acc_d[tm][tn], 0, 0, 0, 0x7f7f7f7f, 0, 0x7f7f7f7f);
        #pragma unroll
        for (int tm = 0; tm < 2; tm++)
            #pragma unroll
            for (int tn = 0; tn < 2; tn++)
                acc_d[tm][tn] = __builtin_amdgcn_mfma_scale_f32_32x32x64_f8f6f4(
                    ap[tm], byy[tn], acc_d[tm][tn], 0, 0, 0, 0x7f7f7f7f, 0, 0x7f7f7f7f);
        #pragma unroll
        for (int tm = 0; tm < 2; tm++)
            #pragma unroll
            for (int tn = 0; tn < 2; tn++)
                acc_d[tm][tn] = __builtin_amdgcn_mfma_scale_f32_32x32x64_f8f6f4(
                    axc[tm], bm2[tn], acc_d[tm][tn], 0, 0, 0, 0x7f7f7f7f, 0, 0x7f7f7f7f);
        #pragma unroll
        for (int tm = 0; tm < 2; tm++)
            #pragma unroll
            for (int tn = 0; tn < 2; tn++)
                acc_c[tm][tn] = __builtin_amdgcn_mfma_scale_f32_32x32x64_f8f6f4(
                    ap[tm], bq[tn], acc_c[tm][tn], 0, 0, 0, 0x7f7f7f7f, 0, 0x7f7f7f7f);

        __syncthreads();
    }

    // epilogue; 32x32 C/D layout (m74/m101): col = lane&31, row = (reg&3)+8*(reg>>2)+4*(lane>>5)
    // nt stores: out is write-once; keep it from evicting ws in L2.
    #pragma unroll
    for (int tm = 0; tm < 2; tm++) {
        #pragma unroll
        for (int tn = 0; tn < 2; tn++) {
            int col = blockCol + wcol + tn * 32 + l31;
            #pragma unroll
            for (int r = 0; r < 16; r++) {
                int rowl = (r & 3) + 8 * (r >> 2) + 4 * kh;
                int row = blockRow + wrow + tm * 32 + rowl;
                float d = fmaxf(acc_d[tm][tn][r], 0.f);
                float c = acc_c[tm][tn][r];
                float res = (c < 0.5f) ? __builtin_nanf("")
                                       : __builtin_sqrtf(d * (float)DDIM / c);
                __builtin_nontemporal_store(res, &out[(size_t)row * MCOLS + col]);
            }
        }
    }
}

// ---------------- fallback: fused single-kernel bf16 (if ws too small) ----------------
#define LDK 40
__global__ __launch_bounds__(256, 2)
void nan_euclid_fused(const float* __restrict__ X, const float* __restrict__ Y,
                      float* __restrict__ out) {
    typedef __attribute__((ext_vector_type(4))) __bf16 bf16x4;
    __shared__ bf16_t s_xx[BM * LDK];
    __shared__ bf16_t s_p [BM * LDK];
    __shared__ bf16_t s_xc[BM * LDK];
    __shared__ bf16_t s_q [BN * LDK];
    __shared__ bf16_t s_yy[BN * LDK];
    __shared__ bf16_t s_m2[BN * LDK];

    const int tid  = threadIdx.x;
    const int lane = tid & 63;
    const int wid  = tid >> 6;
    const int quad = lane >> 4;
    const int r16  = lane & 15;
    const int wrow = (wid >> 1) * 64;
    const int wcol = (wid & 1) * 64;
    const int blockRow = blockIdx.y * BM;
    const int blockCol = blockIdx.x * BN;

    floatx4 acc_d[4][4];
    floatx4 acc_c[4][4];
    #pragma unroll
    for (int i = 0; i < 4; i++)
        #pragma unroll
        for (int j = 0; j < 4; j++)
            #pragma unroll
            for (int r = 0; r < 4; r++) { acc_d[i][j][r] = 0.f; acc_c[i][j][r] = 0.f; }

    for (int kc = 0; kc < DDIM / 32; kc++) {
        const int kbase = kc * 32;
        #pragma unroll
        for (int i = 0; i < 4; i++) {
            int idx = tid + 256 * i;
            int row = idx >> 3;
            int c4  = idx & 7;
            const float4 v = *(const float4*)(X + (size_t)(blockRow + row) * DDIM + kbase + c4 * 4);
            bf16x4 vxc, vxx, vp;
            const float xs[4] = {v.x, v.y, v.z, v.w};
            #pragma unroll
            for (int e = 0; e < 4; e++) {
                float x = xs[e];
                bool miss = __builtin_isnan(x);
                float xc = miss ? 0.f : x;
                vxc[e] = (bf16_t)xc;
                vxx[e] = (bf16_t)(xc * xc);
                vp[e]  = miss ? (bf16_t)0.f : (bf16_t)1.f;
            }
            int off = row * LDK + c4 * 4;
            *(bf16x4*)&s_xc[off] = vxc;
            *(bf16x4*)&s_xx[off] = vxx;
            *(bf16x4*)&s_p [off] = vp;
        }
        #pragma unroll
        for (int i = 0; i < 4; i++) {
            int idx = tid + 256 * i;
            int row = idx >> 3;
            int c4  = idx & 7;
            const float4 v = *(const float4*)(Y + (size_t)(blockCol + row) * DDIM + kbase + c4 * 4);
            bf16x4 vq, vyy, vm2;
            const float ys[4] = {v.x, v.y, v.z, v.w};
            #pragma unroll
            for (int e = 0; e < 4; e++) {
                float y = ys[e];
                bool miss = __builtin_isnan(y);
                float yc = miss ? 0.f : y;
                vq[e]  = miss ? (bf16_t)0.f : (bf16_t)1.f;
                vyy[e] = (bf16_t)(yc * yc);
                vm2[e] = (bf16_t)(-2.f * yc);
            }
            int off = row * LDK + c4 * 4;
            *(bf16x4*)&s_q [off] = vq;
            *(bf16x4*)&s_yy[off] = vyy;
            *(bf16x4*)&s_m2[off] = vm2;
        }
        __syncthreads();
        bf16x8 bq[4], byy[4], bm2[4];
        #pragma unroll
        for (int tn = 0; tn < 4; tn++) {
            int off = (wcol + tn * 16 + r16) * LDK + quad * 8;
            bq[tn]  = *(const bf16x8*)&s_q [off];
            byy[tn] = *(const bf16x8*)&s_yy[off];
            bm2[tn] = *(const bf16x8*)&s_m2[off];
        }
        #pragma unroll
        for (int tm = 0; tm < 4; tm++) {
            int off = (wrow + tm * 16 + r16) * LDK + quad * 8;
            bf16x8 axx = *(const bf16x8*)&s_xx[off];
            bf16x8 ap  = *(const bf16x8*)&s_p [off];
            bf16x8 axc = *(const bf16x8*)&s_xc[off];
            #pragma unroll
            for (int tn = 0; tn < 4; tn++) {
                acc_d[tm][tn] = __builtin_amdgcn_mfma_f32_16x16x32_bf16(axx, bq[tn],  acc_d[tm][tn], 0, 0, 0);
                acc_d[tm][tn] = __builtin_amdgcn_mfma_f32_16x16x32_bf16(ap,  byy[tn], acc_d[tm][tn], 0, 0, 0);
                acc_d[tm][tn] = __builtin_amdgcn_mfma_f32_16x16x32_bf16(axc, bm2[tn], acc_d[tm][tn], 0, 0, 0);
                acc_c[tm][tn] = __builtin_amdgcn_mfma_f32_16x16x32_bf16(ap,  bq[tn],  acc_c[tm][tn], 0, 0, 0);
            }
        }
        __syncthreads();
    }
    #pragma unroll
    for (int tm = 0; tm < 4; tm++) {
        #pragma unroll
        for (int tn = 0; tn < 4; tn++) {
            int col = blockCol + wcol + tn * 16 + r16;
            #pragma unroll
            for (int r = 0; r < 4; r++) {
                int row = blockRow + wrow + tm * 16 + quad * 4 + r;
                float d = acc_d[tm][tn][r];
                float c = acc_c[tm][tn][r];
                d = fmaxf(d, 0.f);
                float res = (c < 0.5f) ? __builtin_nanf("")
                                       : __builtin_sqrtf(d * (float)DDIM / c);
                out[(size_t)row * MCOLS + col] = res;
            }
        }
    }
}

extern "C" void kernel_launch(void* const* d_in, const int* in_sizes, int n_in,
                              void* d_out, int out_size, void* d_ws, size_t ws_size,
                              hipStream_t stream) {
    const float* X = (const float*)d_in[0];
    const float* Y = (const float*)d_in[1];
    float* out = (float*)d_out;

    if (ws_size >= WS_NEEDED) {
        char* ws = (char*)d_ws;
        convert_planes_mx<<<dim3(2048), dim3(256), 0, stream>>>(X, Y, ws);
        dim3 grid(MCOLS / BN, NROWS / BM);
        nan_euclid_mx<<<grid, dim3(256), 0, stream>>>(ws, out);
    } else {
        dim3 grid(MCOLS / BN, NROWS / BM);
        nan_euclid_fused<<<grid, dim3(256), 0, stream>>>(X, Y, out);
    }
}